// Round 9
// baseline (129.694 us; speedup 1.0000x reference)
//
#include <hip/hip_runtime.h>
#include <hip/hip_bf16.h>

// SoftRAM attention: S=128, B=256 bits, H=16 heads, NB=12 bits/neuron, PB=7.
// addr(i,j,h,n) = aq_i ^ ak_j ^ ap_{i-j} (disjoint bit groups per (h,n)).
//
// R9: two dispatches.
//  Kernel A: pure-BW sign-pack. memory (64MB f32) -> 2MB bit-LUT in ws via
//   __ballot (bit l of word 4T+c = sign(mem[256T+4l+c])). The implied address
//   permutation tau (r2..7->bit idx, r0,1,8..11->word idx) is GF2-linear.
//   Also packs tokens (block 0) so kernel B's preamble is 4KB.
//  Kernel B: per-n block, wave=head. Stage 512B/head from L2, place u32 words
//   under linear bank-fold psi; tables store 12-bit codes
//   code(r) = psi(w32(r)) | bit5(r)<<7  (all linear => XOR-combinable).
//   Gather = ds_read_b32 + shift. Sweeps identical to verified R8 logic.

#define S 128
#define B 256
#define H 16
#define NB 12

// ---- Kernel A: sign-pack + token pack ----
__global__ __launch_bounds__(256) void softram_pack(
    const float* __restrict__ memory,          // [H*B*4096]
    const int* __restrict__ tokens,            // [S,B]
    unsigned long long* __restrict__ lut64,    // [262144] ws
    unsigned int* __restrict__ tokpack)        // [8*128]  ws
{
    const int bx = blockIdx.x, tid = threadIdx.x;
    const int w = tid >> 6, lane = tid & 63;
    const float4* mp = (const float4*)memory;
    #pragma unroll
    for (int it = 0; it < 16; ++it) {
        int chunk = bx * 64 + w * 16 + it;         // 256-float chunk
        float4 v = mp[chunk * 64 + lane];
        unsigned long long b0 = __ballot(v.x > 0.f);
        unsigned long long b1 = __ballot(v.y > 0.f);
        unsigned long long b2 = __ballot(v.z > 0.f);
        unsigned long long b3 = __ballot(v.w > 0.f);
        unsigned long long sel = b0;
        sel = (lane == 1) ? b1 : sel;
        sel = (lane == 2) ? b2 : sel;
        sel = (lane == 3) ? b3 : sel;
        if (lane < 4) lut64[chunk * 4 + lane] = sel;
    }
    if (bx == 0) {   // token pack, transposed: tokpack[w*128 + i]
        #pragma unroll
        for (int q = 0; q < 4; ++q) {
            int e = tid + (q << 8);
            int i = e >> 3, ww = e & 7;
            const int4* tp = (const int4*)tokens;
            unsigned vv = 0;
            #pragma unroll
            for (int u = 0; u < 8; ++u) {
                int4 x = tp[i * 64 + ww * 8 + u];
                vv |= (unsigned)(x.x & 1) << (4 * u + 0);
                vv |= (unsigned)(x.y & 1) << (4 * u + 1);
                vv |= (unsigned)(x.z & 1) << (4 * u + 2);
                vv |= (unsigned)(x.w & 1) << (4 * u + 3);
            }
            tokpack[ww * 128 + i] = vv;
        }
    }
}

// code(r): u32-word index (psi-folded, 7 bits) | bit-in-word << 7 (5 bits).
// w32 bits: [r7, r0, r1, r8, r9, r10, r11]; psi folds bits 5,6 into 1,2.
__device__ __forceinline__ unsigned codef(unsigned r) {
    unsigned cw = ((r >> 7) & 1u) | ((r & 3u) << 1) | (((r >> 8) & 15u) << 3);
    cw ^= ((cw >> 5) & 3u) << 1;
    return cw | (((r >> 2) & 31u) << 7);
}

// ---- Kernel B: main compute ----
__global__ __launch_bounds__(1024) void softram_main(
    const unsigned long long* __restrict__ lut64,
    const unsigned int* __restrict__ tokpack,
    const int* __restrict__ connections,       // [H,B,NB]
    int* __restrict__ out)                     // [S,B]
{
    const int n    = blockIdx.x;
    const int tid  = threadIdx.x;
    const int h    = tid >> 6;                 // wave == head
    const int lane = tid & 63;

    __shared__ unsigned int   lutw[H][128];    // 8 KB sign words (psi layout)
    __shared__ unsigned int   tokT[8][S];      // 4 KB
    __shared__ unsigned short aqc[H][S];       // 4 KB code(aq)
    __shared__ unsigned short akc[H][S];       // 4 KB code(ak)
    __shared__ unsigned short apc[H][S];       // 4 KB code(ap) by distance
    __shared__ int            conns[H][NB];    // 768 B
    __shared__ unsigned int   parts[H][4];     // 256 B

    tokT[tid >> 7][tid & 127] = tokpack[tid];
    if (tid < H * NB) {
        int hh = tid / NB, b = tid - hh * NB;
        conns[hh][b] = connections[hh * (B * NB) + n * NB + b];
    }
    __syncthreads();   // barrier #1 (drains 4KB+3KB L2 reads only)

    // ---- stage own head's packed row (512 B) into psi-placed u32 words ----
    {
        unsigned long long wrow = lut64[(size_t)((h << 8) | n) * 64 + lane];
        unsigned wpos = (unsigned)(2 * lane);
        wpos ^= ((wpos >> 5) & 3u) << 1;       // psi; preserves bit0 -> even
        lutw[h][wpos]     = (unsigned)wrow;
        lutw[h][wpos + 1] = (unsigned)(wrow >> 32);
    }

    // ---- per-head masks (wave-uniform) ----
    unsigned qmask = 0, kmask = 0, pmask = 0;
    #pragma unroll
    for (int b = 0; b < NB; ++b) {
        int c = conns[h][b];
        qmask |= (unsigned)(c < 256) << b;
        kmask |= (unsigned)(c >= 256 && c < 512) << b;
        pmask |= (unsigned)(c >= 512) << b;
    }

    // ---- per-head code tables ----
    #pragma unroll
    for (int e = 0; e < 2; ++e) {
        int ii = lane + 64 * e;
        unsigned aq = 0, ak = 0, ap = 0;
        #pragma unroll
        for (int b = 0; b < NB; ++b) {
            int c = conns[h][b];               // wave-uniform branches
            if (c < 256) {
                aq |= ((tokT[c >> 5][ii] >> (c & 31)) & 1u) << b;
            } else if (c < 512) {
                int c2 = c - 256;
                ak |= ((tokT[c2 >> 5][ii] >> (c2 & 31)) & 1u) << b;
            } else {
                ap |= ((unsigned)(ii >> (c - 512)) & 1u) << b;
            }
        }
        aqc[h][ii] = (unsigned short)codef(aq);
        akc[h][ii] = (unsigned short)codef(ak);
        apc[h][ii] = (unsigned short)codef(ap);
    }

    // ---- sweep (inputs all self-written or pre-barrier -> no barrier) ----
    const unsigned* __restrict__ lrow = &lutw[h][0];
    unsigned long long rlo = 0, rhi = 0;

    if (pmask == 0) {
        int qb = __popc(qmask), kb = __popc(kmask);
        bool sideQ = (qb <= kb);
        unsigned smask = sideQ ? qmask : kmask;
        int m = sideQ ? qb : kb;               // <= 6
        unsigned spread = 0;
        {
            unsigned k = (unsigned)lane;
            #pragma unroll
            for (int b = 0; b < NB; ++b) {
                if ((smask >> b) & 1u) { spread |= (k & 1u) << b; k >>= 1; }
            }
        }
        const unsigned spv = codef(spread);
        const int lim = 1 << m;
        const bool lv = (lane < lim);
        const unsigned long long vmask =
            (lim >= 64) ? ~0ull : ((1ull << lim) - 1ull);

        if (sideQ) {
            // lanes = Q-subspace; sweep keys j; running per-lane parity.
            unsigned acc = 0;
            for (int s8 = 0; s8 < 16; ++s8) {
                uint4 uq = *(const uint4*)&aqc[h][s8 * 8];
                uint4 uk = *(const uint4*)&akc[h][s8 * 8];
                #pragma unroll
                for (int t = 0; t < 8; ++t) {
                    int j = s8 * 8 + t;
                    unsigned cwk = ((const unsigned*)&uk)[t >> 1];
                    unsigned cwq = ((const unsigned*)&uq)[t >> 1];
                    unsigned akv = (cwk >> ((t & 1) * 16)) & 0xffffu;
                    unsigned aqv = (cwq >> ((t & 1) * 16)) & 0xffffu;
                    unsigned vt = akv ^ spv;
                    acc ^= lrow[vt & 127] >> (vt >> 7);
                    unsigned long long accB = __ballot((acc & 1u) != 0u);
                    unsigned long long mm   = __ballot(lv && (spv == aqv));
                    unsigned long long bit  = ((accB & mm & vmask) != 0ull);
                    if (j < 64) rlo |= bit << j; else rhi |= bit << (j - 64);
                }
            }
        } else {
            // lanes = K-subspace; sweep queries i; c = prefix parity per class.
            unsigned c = 0;
            for (int s8 = 0; s8 < 16; ++s8) {
                uint4 uq = *(const uint4*)&aqc[h][s8 * 8];
                uint4 uk = *(const uint4*)&akc[h][s8 * 8];
                #pragma unroll
                for (int t = 0; t < 8; ++t) {
                    int i = s8 * 8 + t;
                    unsigned cwk = ((const unsigned*)&uk)[t >> 1];
                    unsigned cwq = ((const unsigned*)&uq)[t >> 1];
                    unsigned akv = (cwk >> ((t & 1) * 16)) & 0xffffu;
                    unsigned aqv = (cwq >> ((t & 1) * 16)) & 0xffffu;
                    c ^= (unsigned)(lv && (spv == akv));   // include key j=i
                    unsigned vt = aqv ^ spv;
                    unsigned sb = lrow[vt & 127] >> (vt >> 7);
                    unsigned long long mb = __ballot((c & sb & 1u) != 0u);
                    unsigned long long bit = (unsigned long long)
                        (__popcll(mb & vmask) & 1ull);
                    if (i < 64) rlo |= bit << i; else rhi |= bit << (i - 64);
                }
            }
        }
    } else {
        // P fallback: lane = key j (and j+64); sweep queries i.
        const unsigned ak0 = akc[h][lane];
        const unsigned ak1 = akc[h][lane + 64];
        for (int s8 = 0; s8 < 16; ++s8) {
            uint4 uq = *(const uint4*)&aqc[h][s8 * 8];
            #pragma unroll
            for (int t = 0; t < 8; ++t) {
                int i = s8 * 8 + t;
                unsigned cwq = ((const unsigned*)&uq)[t >> 1];
                unsigned aqv = (cwq >> ((t & 1) * 16)) & 0xffffu;
                unsigned ap0 = apc[h][(i - lane) & 127];
                unsigned t0  = aqv ^ ak0 ^ ap0;
                unsigned v0  = lrow[t0 & 127] >> (t0 >> 7);
                unsigned long long m0 = __ballot((v0 & 1u) != 0u);
                unsigned long long pre0 =
                    (i >= 63) ? ~0ull : ((2ull << i) - 1ull);
                unsigned cnt = (unsigned)__popcll(m0 & pre0);
                if (i >= 64) {
                    unsigned ap1 = apc[h][(i - lane - 64) & 127];
                    unsigned t1  = aqv ^ ak1 ^ ap1;
                    unsigned v1  = lrow[t1 & 127] >> (t1 >> 7);
                    unsigned long long m1 = __ballot((v1 & 1u) != 0u);
                    unsigned long long pre1 =
                        (i >= 127) ? ~0ull : ((2ull << (i - 64)) - 1ull);
                    cnt += (unsigned)__popcll(m1 & pre1);
                }
                unsigned long long bit = cnt & 1u;
                if (i < 64) rlo |= bit << i; else rhi |= bit << (i - 64);
            }
        }
    }

    if (lane == 0) {
        parts[h][0] = (unsigned)rlo;
        parts[h][1] = (unsigned)(rlo >> 32);
        parts[h][2] = (unsigned)rhi;
        parts[h][3] = (unsigned)(rhi >> 32);
    }
    __syncthreads();   // barrier #2

    if (tid < S) {
        int i = tid, tot = 0;
        #pragma unroll
        for (int hh = 0; hh < H; ++hh)
            tot += (parts[hh][i >> 5] >> (i & 31)) & 1;
        out[i * B + n] = (tot > (H / 2)) ? 1 : 0;
    }
}

extern "C" void kernel_launch(void* const* d_in, const int* in_sizes, int n_in,
                              void* d_out, int out_size, void* d_ws, size_t ws_size,
                              hipStream_t stream) {
    const int*   tokens      = (const int*)d_in[0];
    const float* memory      = (const float*)d_in[1];
    const int*   connections = (const int*)d_in[2];
    int*         out         = (int*)d_out;
    (void)in_sizes; (void)n_in; (void)out_size; (void)ws_size;

    unsigned long long* lut64   = (unsigned long long*)d_ws;            // 2 MB
    unsigned int*       tokpack = (unsigned int*)((char*)d_ws + (2u << 20)); // 4 KB

    softram_pack<<<1024, 256, 0, stream>>>(memory, tokens, lut64, tokpack);
    softram_main<<<B, 1024, 0, stream>>>(lut64, tokpack, connections, out);
}

// Round 10
// 124.988 us; speedup vs baseline: 1.0377x; 1.0377x over previous
//
#include <hip/hip_runtime.h>
#include <hip/hip_bf16.h>

// SoftRAM attention: S=128, B=256 bits, H=16 heads, NB=12 bits/neuron, PB=7.
// addr(i,j,h,n) = aq_i | ak_j | ap_{i-j} (disjoint bit groups per (h,n)).
//
// R10: prefix-of-words algorithm. For no-P heads:
//   result_i = bit qidx_i of W_i,  W_i = XOR_{j<=i} Trow[kidx_j]
// (Trow[k] = 2^qb-bit word, bit a = sign at aq=a,ak=k). W_i via 6-step
// shuffle XOR scan -> NO per-key inner loop. Trow built with exactly 64
// ballot iterations for any qb<=6 (lane = inner|outer_low bits, iter =
// outer_high 6 bits, lane e keeps word e). qb>=7 uses the mirror (Srow by
// q-point + per-k-class count-parity u32 scan + popcount). P-heads: direct
// d-sweep (ap_d wave-uniform, 2 bit-gathers/iter). Whole kernel is then
// HBM-bound (~10 us for the 64 MB memory read), stage overlapped per-wave.

#define S 128
#define B 256
#define H 16
#define NB 12

__device__ __forceinline__ unsigned pdep12(unsigned val, unsigned mask) {
    unsigned r = 0; int t = 0;
    #pragma unroll
    for (int b = 0; b < NB; ++b) {
        if ((mask >> b) & 1u) { r |= ((val >> t) & 1u) << b; ++t; }
    }
    return r;
}

__device__ __forceinline__ unsigned scan_xor32(unsigned x, int lane) {
    #pragma unroll
    for (int off = 1; off < 64; off <<= 1) {
        unsigned y = __shfl_up(x, off, 64);
        x ^= (lane >= off) ? y : 0u;
    }
    return x;   // inclusive prefix-XOR over 64 lanes
}

__global__ __launch_bounds__(1024) void softram_kernel(
    const int* __restrict__ tokens,        // [S,B] 0/1
    const float* __restrict__ memory,      // [H,B,4096]
    const int* __restrict__ connections,   // [H,B,NB]
    int* __restrict__ out)                 // [S,B] 0/1
{
    const int n    = blockIdx.x;
    const int tid  = threadIdx.x;
    const int h    = tid >> 6;             // wave == head
    const int lane = tid & 63;

    __shared__ unsigned long long packA[H * 64];   // 8 KB: linear sign bits
    __shared__ unsigned long long trowA[H * 64];   // 8 KB: Trow/Srow words
    __shared__ unsigned int       tokT[8][S];      // 4 KB
    __shared__ unsigned short     aksv[H * 128];   // 4 KB spread ak (P path)
    __shared__ unsigned short     apsv[H * 128];   // 4 KB spread ap by dist
    __shared__ int                conns[H][NB];    // 768 B
    __shared__ unsigned int       parts[H][4];     // 256 B

    // ---- token pack (transposed) + conns ----
    {
        int i = tid >> 3, w = tid & 7;
        const int4* tp = (const int4*)tokens;
        unsigned v = 0;
        #pragma unroll
        for (int u = 0; u < 8; ++u) {
            int4 x = tp[i * 64 + w * 8 + u];
            v |= (unsigned)(x.x & 1) << (4 * u + 0);
            v |= (unsigned)(x.y & 1) << (4 * u + 1);
            v |= (unsigned)(x.z & 1) << (4 * u + 2);
            v |= (unsigned)(x.w & 1) << (4 * u + 3);
        }
        tokT[w][i] = v;
    }
    if (tid < H * NB) {
        int hh = tid / NB, b = tid - hh * NB;
        conns[hh][b] = connections[hh * (B * NB) + n * NB + b];
    }
    __syncthreads();   // barrier #1

    // ---- stage own head's row; ballot-pack linear: packA bit x = sign(mem[x]) ----
    const float* row = memory + ((size_t)(h * 256 + n) << 12);
    unsigned long long pk = 0;
    #pragma unroll
    for (int co = 0; co < 8; ++co) {
        float v[8];
        #pragma unroll
        for (int ci = 0; ci < 8; ++ci) v[ci] = row[(co * 8 + ci) * 64 + lane];
        #pragma unroll
        for (int ci = 0; ci < 8; ++ci) {
            unsigned long long bal = __ballot(v[ci] > 0.0f);
            if (lane == co * 8 + ci) pk = bal;
        }
    }
    packA[h * 64 + lane] = pk;     // self-wave write; in-order LDS => visible
    const unsigned* pk32 = (const unsigned*)&packA[h * 64];

    // ---- per-head masks + per-lane indices (2 halves: ii = lane, lane+64) ----
    unsigned qmask = 0, kmask = 0, pmask = 0;
    #pragma unroll
    for (int b = 0; b < NB; ++b) {
        int c = conns[h][b];
        qmask |= (unsigned)(c < 256) << b;
        kmask |= (unsigned)(c >= 256 && c < 512) << b;
        pmask |= (unsigned)(c >= 512) << b;
    }
    unsigned qi0 = 0, qi1 = 0, ki0 = 0, ki1 = 0;
    unsigned aqv0 = 0, aqv1 = 0, akv0 = 0, akv1 = 0, apv0 = 0, apv1 = 0;
    int qc = 0, kc = 0;
    #pragma unroll
    for (int b = 0; b < NB; ++b) {
        int c = conns[h][b];
        if (c < 256) {
            unsigned b0 = (tokT[c >> 5][lane]      >> (c & 31)) & 1u;
            unsigned b1 = (tokT[c >> 5][lane + 64] >> (c & 31)) & 1u;
            qi0 |= b0 << qc; qi1 |= b1 << qc;
            aqv0 |= b0 << b;  aqv1 |= b1 << b;  ++qc;
        } else if (c < 512) {
            int c2 = c - 256;
            unsigned b0 = (tokT[c2 >> 5][lane]      >> (c2 & 31)) & 1u;
            unsigned b1 = (tokT[c2 >> 5][lane + 64] >> (c2 & 31)) & 1u;
            ki0 |= b0 << kc; ki1 |= b1 << kc;
            akv0 |= b0 << b;  akv1 |= b1 << b;  ++kc;
        } else {
            int t = c - 512;
            apv0 |= (((unsigned)lane >> t) & 1u) << b;
            apv1 |= ((((unsigned)lane + 64u) >> t) & 1u) << b;
        }
    }
    aksv[h * 128 + lane]      = (unsigned short)akv0;
    aksv[h * 128 + lane + 64] = (unsigned short)akv1;
    apsv[h * 128 + lane]      = (unsigned short)apv0;
    apsv[h * 128 + lane + 64] = (unsigned short)apv1;

    const int qb = __popc(qmask), kb = __popc(kmask);
    unsigned rb0 = 0, rb1 = 0;

    if (pmask == 0) {
        // ---- build Trow (A) / Srow (B): 64 ballot iterations, lane e keeps word e ----
        const bool pathA = (qb <= 6);
        const unsigned maskI = pathA ? qmask : kmask;
        const unsigned maskO = pathA ? kmask : qmask;
        const int bi = pathA ? qb : kb;          // <= 6 (B: kb <= 5)
        const unsigned im = (1u << bi) - 1u;
        const unsigned spl = pdep12((unsigned)lane & im, maskI)
                           | pdep12((unsigned)lane >> bi, maskO);
        const unsigned spE = pdep12((unsigned)lane << (6 - bi), maskO);

        unsigned long long tr = 0;
        #pragma unroll
        for (int e = 0; e < 64; ++e) {
            unsigned spe = __builtin_amdgcn_readlane(spE, e);
            unsigned x = spe ^ spl;
            unsigned w = pk32[x >> 5];
            unsigned long long bal = __ballot(((w >> (x & 31)) & 1u) != 0u);
            if (lane == e) tr = bal;
        }
        trowA[h * 64 + lane] = tr;               // self-wave; visible below

        const unsigned long long* tw = &trowA[h * 64];
        const int olb = 6 - bi;
        const unsigned olm = (1u << olb) - 1u;

        if (pathA) {
            const unsigned long long wm =
                (bi == 6) ? ~0ull : ((1ull << (1u << bi)) - 1ull);
            unsigned long long w0 = tw[ki0 >> olb];
            unsigned long long T0 = (w0 >> ((ki0 & olm) << bi)) & wm;
            unsigned long long w1 = tw[ki1 >> olb];
            unsigned long long T1 = (w1 >> ((ki1 & olm) << bi)) & wm;
            unsigned t0lo = scan_xor32((unsigned)T0, lane);
            unsigned t0hi = scan_xor32((unsigned)(T0 >> 32), lane);
            unsigned tlo63 = __shfl(t0lo, 63, 64);
            unsigned thi63 = __shfl(t0hi, 63, 64);
            unsigned t1lo = scan_xor32((unsigned)T1, lane) ^ tlo63;
            unsigned t1hi = scan_xor32((unsigned)(T1 >> 32), lane) ^ thi63;
            unsigned long long W0 = ((unsigned long long)t0hi << 32) | t0lo;
            unsigned long long W1 = ((unsigned long long)t1hi << 32) | t1lo;
            rb0 = (unsigned)(W0 >> qi0) & 1u;    // qi < 2^bi <= 64
            rb1 = (unsigned)(W1 >> qi1) & 1u;
        } else {
            // mirror: Cvec = per-k-class count parity (u32), Srow slice by qidx
            const unsigned sm = (unsigned)((1ull << (1u << bi)) - 1ull);
            unsigned C0 = scan_xor32(1u << ki0, lane);   // ki < 2^kb <= 32
            unsigned c63 = __shfl(C0, 63, 64);
            unsigned C1 = scan_xor32(1u << ki1, lane) ^ c63;
            unsigned long long w0 = tw[qi0 >> olb];
            unsigned Sl0 = (unsigned)(w0 >> ((qi0 & olm) << bi)) & sm;
            unsigned long long w1 = tw[qi1 >> olb];
            unsigned Sl1 = (unsigned)(w1 >> ((qi1 & olm) << bi)) & sm;
            rb0 = (unsigned)__popc(Sl0 & C0) & 1u;
            rb1 = (unsigned)__popc(Sl1 & C1) & 1u;
        }
    } else {
        // ---- P fallback: d-sweep, lanes = queries (i=lane, i=lane+64) ----
        const unsigned short* aks = &aksv[h * 128];
        const unsigned short* aps = &apsv[h * 128];
        unsigned acc0 = 0, acc1 = 0;
        #pragma unroll 8
        for (int d = 0; d < 64; ++d) {
            unsigned apd = aps[d];                         // broadcast
            unsigned ak0 = aks[(lane - d) & 127];
            unsigned x0 = aqv0 ^ ak0 ^ apd;
            unsigned bit0 = (pk32[x0 >> 5] >> (x0 & 31)) & 1u;
            acc0 ^= (lane >= d) ? bit0 : 0u;
            unsigned ak1 = aks[(lane + 64 - d) & 127];
            unsigned x1 = aqv1 ^ ak1 ^ apd;
            acc1 ^= (pk32[x1 >> 5] >> (x1 & 31)) & 1u;     // always valid
        }
        #pragma unroll 8
        for (int d = 64; d < 128; ++d) {
            unsigned apd = aps[d];
            unsigned ak1 = aks[(lane + 64 - d) & 127];
            unsigned x1 = aqv1 ^ ak1 ^ apd;
            unsigned bit1 = (pk32[x1 >> 5] >> (x1 & 31)) & 1u;
            acc1 ^= (lane + 64 >= d) ? bit1 : 0u;
        }
        rb0 = acc0 & 1u;
        rb1 = acc1 & 1u;
    }

    // ---- collect 128 result bits for this head ----
    unsigned long long blo = __ballot(rb0 != 0u);
    unsigned long long bhi = __ballot(rb1 != 0u);
    if (lane == 0) {
        parts[h][0] = (unsigned)blo;
        parts[h][1] = (unsigned)(blo >> 32);
        parts[h][2] = (unsigned)bhi;
        parts[h][3] = (unsigned)(bhi >> 32);
    }
    __syncthreads();   // barrier #2

    // ---- majority vote across 16 heads ----
    if (tid < S) {
        int i = tid, tot = 0;
        #pragma unroll
        for (int hh = 0; hh < H; ++hh)
            tot += (parts[hh][i >> 5] >> (i & 31)) & 1;
        out[i * B + n] = (tot > (H / 2)) ? 1 : 0;
    }
}

extern "C" void kernel_launch(void* const* d_in, const int* in_sizes, int n_in,
                              void* d_out, int out_size, void* d_ws, size_t ws_size,
                              hipStream_t stream) {
    const int*   tokens      = (const int*)d_in[0];
    const float* memory      = (const float*)d_in[1];
    const int*   connections = (const int*)d_in[2];
    int*         out         = (int*)d_out;
    (void)in_sizes; (void)n_in; (void)out_size; (void)d_ws; (void)ws_size;

    softram_kernel<<<B, 1024, 0, stream>>>(tokens, memory, connections, out);
}